// Round 6
// baseline (91.893 us; speedup 1.0000x reference)
//
#include <hip/hip_runtime.h>

#define NB 16     // batch
#define CD 128    // channels
#define HW 4096   // spatial L
#define DD 512    // projected dim
#define KC 64     // clusters

typedef __attribute__((ext_vector_type(8))) short bfrag;           // 8 bf16 (4 VGPR)
typedef __attribute__((ext_vector_type(8))) unsigned short upk8;   // 8 bf16
typedef __attribute__((ext_vector_type(4))) float facc;            // MFMA acc
typedef __attribute__((ext_vector_type(4))) unsigned short upk4;   // 4 bf16

__device__ __forceinline__ unsigned short f2bf(float f) {
  union { float f; unsigned u; } v; v.f = f;
  unsigned r = v.u + 0x7fffu + ((v.u >> 16) & 1u);   // RNE
  return (unsigned short)(r >> 16);
}
__device__ __forceinline__ float bf2f(unsigned short h) {
  union { unsigned u; float f; } v; v.u = ((unsigned)h) << 16; return v.f;
}

// ---------- prep: centroid L2-normalize -> bf16 ; conv_w -> bf16 ----------
__global__ __launch_bounds__(256) void k_prep(const float* __restrict__ conv_w,
                                              const float* __restrict__ centroids,
                                              unsigned short* __restrict__ Wb,
                                              unsigned short* __restrict__ Cb) {
  int b = blockIdx.x, t = threadIdx.x;
  if (b < KC) {
    const float* row = centroids + (size_t)b * DD;
    float v0 = row[t], v1 = row[t + 256];
    float ss = v0 * v0 + v1 * v1;
    #pragma unroll
    for (int off = 32; off; off >>= 1) ss += __shfl_xor(ss, off);
    __shared__ float red[4];
    if ((t & 63) == 0) red[t >> 6] = ss;
    __syncthreads();
    float tot = red[0] + red[1] + red[2] + red[3];
    float inv = 1.0f / fmaxf(sqrtf(tot), 1e-12f);
    Cb[(size_t)b * DD + t]       = f2bf(v0 * inv);
    Cb[(size_t)b * DD + t + 256] = f2bf(v1 * inv);
  } else {
    int i = (b - KC) * 2048 + t * 8;            // 32 blocks cover 65536 elems
    const float4* src = (const float4*)(conv_w + i);
    float4 a = src[0], c = src[1];
    upk4 w0, w1;
    w0[0] = f2bf(a.x); w0[1] = f2bf(a.y); w0[2] = f2bf(a.z); w0[3] = f2bf(a.w);
    w1[0] = f2bf(c.x); w1[1] = f2bf(c.y); w1[2] = f2bf(c.z); w1[3] = f2bf(c.w);
    *(upk4*)(Wb + i)     = w0;
    *(upk4*)(Wb + i + 4) = w1;
  }
}

// ---------- fused xnorm + projection + logits/exp ----------
// Per block (n, l-chunk of 128):
//   P1-P3: x fp32 -> x-hat bf16 (Xn, LDS)
//   P4 (4 d-chunks): f = Xn*Wb^T + b -> fT global + fbuf LDS;
//                    e_acc += Cb_chunk * fbuf^T  (accumulate logits over d)
//   P5: e = exp(e_acc) -> bf16 e global + rowsum partials -> psums
// LDS: A [0,32K): xt / Ws / fbuf ; B [32K,64K): psum / Xn ; C [64K,80K): Cbs / ps
__global__ __launch_bounds__(512, 4) void k_xproj(const float* __restrict__ x,
                                                  const unsigned short* __restrict__ Wb,
                                                  const unsigned short* __restrict__ Cb,
                                                  const float* __restrict__ conv_b,
                                                  unsigned short* __restrict__ fT,
                                                  unsigned short* __restrict__ e,
                                                  float* __restrict__ psums) {
  __shared__ __align__(16) char smem[81920];
  char* xt   = smem;                      // (c,l): byte = c*256 + ((l*2)^((c&7)<<4))
  char* Xn   = smem + 32768;              // (l,c): byte = l*256 + ((c*2)^((l&7)<<4))
  float* psum = (float*)(smem + 32768);   // [4][128], dead before Xn writes
  char* Ws   = smem;                      // (d,c) chunk, aliases xt (dead after P3)
  char* fbuf = smem;                      // (l,d) chunk, aliases Ws (dead after f-MFMA)
  char* Cbs  = smem + 65536;              // (k,d) chunk: byte = k*256 + ((d*2)^((k&7)<<4))
  float* ps  = (float*)(smem + 65536);    // [64][4], aliases Cbs (dead after loop)
  int n = blockIdx.y, l0 = blockIdx.x * 128;
  int t = threadIdx.x, lane = t & 63, wid = t >> 6;

  // P1: load x rows (c, 512B each) -> bf16 -> xt swizzled
  {
    int c = t >> 2;
    const float* xrow = x + ((size_t)n * CD + c) * HW + l0;
    #pragma unroll
    for (int j = 0; j < 8; j++) {
      int fq = (t & 3) + 4 * j;                 // float4 slot; l = fq*4
      float4 v = *(const float4*)(xrow + fq * 4);
      upk4 w;
      w[0] = f2bf(v.x); w[1] = f2bf(v.y); w[2] = f2bf(v.z); w[3] = f2bf(v.w);
      *(upk4*)(xt + c * 256 + ((fq * 8) ^ ((c & 7) << 4))) = w;
    }
  }
  __syncthreads();
  // P2: per-l sum of squares (partials over 4 c-ranges)
  {
    int l = t & 127, ch = t >> 7;
    float ss = 0.f;
    #pragma unroll
    for (int i = 0; i < 32; i++) {
      int c = ch * 32 + i;
      float v = bf2f(*(const unsigned short*)(xt + c * 256 + (((l * 2)) ^ ((c & 7) << 4))));
      ss += v * v;
    }
    psum[ch * 128 + l] = ss;
  }
  __syncthreads();
  // P3: inv per l; write Xn (l,c) swizzled
  {
    int l = t >> 2, cb = (t & 3) * 32;
    float tot = psum[l] + psum[128 + l] + psum[256 + l] + psum[384 + l];
    float inv = 1.0f / fmaxf(sqrtf(tot), 1e-12f);
    __syncthreads();                            // psum reads done before Xn writes
    #pragma unroll
    for (int g = 0; g < 4; g++) {
      int cc = cb + g * 8;
      upk8 w;
      #pragma unroll
      for (int i = 0; i < 8; i++) {
        int c = cc + i;
        float v = bf2f(*(const unsigned short*)(xt + c * 256 + (((l * 2)) ^ ((c & 7) << 4))));
        w[i] = f2bf(v * inv);
      }
      *(upk8*)(Xn + l * 256 + ((cc * 2) ^ ((l & 7) << 4))) = w;
    }
  }

  // P4: 4 d-chunks of 128. 8 waves 2x4: f-tile 64l x 32d; e-tile 32k x 32l.
  int wr = wid >> 2, wc = wid & 3;
  int r0 = (lane >> 4) << 2, cl = lane & 15;
  facc e_acc[2][2];
  facc zero = {0.f, 0.f, 0.f, 0.f};
  e_acc[0][0] = zero; e_acc[0][1] = zero; e_acc[1][0] = zero; e_acc[1][1] = zero;

  for (int dch = 0; dch < 4; dch++) {
    __syncthreads();                            // xt/fbuf/Cbs reads done
    {   // stage Ws (Wb chunk, 128d x 128c) swizzled
      int d = t >> 2;
      const unsigned short* wrow = Wb + (size_t)(dch * 128 + d) * CD;
      #pragma unroll
      for (int j = 0; j < 4; j++) {
        int ch16 = (t & 3) + 4 * j;             // 16B chunk; c0 = ch16*8
        bfrag v = *(const bfrag*)(wrow + ch16 * 8);
        *(bfrag*)(Ws + d * 256 + ((ch16 * 16) ^ ((d & 7) << 4))) = v;
      }
    }
    {   // stage Cbs (Cb chunk, 64k x 128d) swizzled — FULL row (2 chunks/thread)
      int k = t >> 3;
      #pragma unroll
      for (int j = 0; j < 2; j++) {
        int c0 = ((t & 7) + 8 * j) * 8;         // element offset 0..120
        bfrag v = *(const bfrag*)(Cb + (size_t)k * DD + dch * 128 + c0);
        *(bfrag*)(Cbs + k * 256 + ((c0 * 2) ^ ((k & 7) << 4))) = v;
      }
    }
    __syncthreads();
    // f-MFMA: acc = Xn(128l x 128c) * Ws(128d x 128c)^T, wave tile 64l x 32d
    facc acc[4][2];
    #pragma unroll
    for (int m = 0; m < 4; m++) { acc[m][0] = zero; acc[m][1] = zero; }
    #pragma unroll
    for (int kk = 0; kk < 128; kk += 32) {
      int c0 = kk + ((lane >> 4) << 3);
      bfrag af[4], bf[2];
      #pragma unroll
      for (int m = 0; m < 4; m++) {
        int row = wr * 64 + m * 16 + (lane & 15);
        af[m] = *(const bfrag*)(Xn + row * 256 + ((c0 * 2) ^ ((row & 7) << 4)));
      }
      #pragma unroll
      for (int j = 0; j < 2; j++) {
        int drow = wc * 32 + j * 16 + (lane & 15);
        bf[j] = *(const bfrag*)(Ws + drow * 256 + ((c0 * 2) ^ ((drow & 7) << 4)));
      }
      #pragma unroll
      for (int m = 0; m < 4; m++)
        #pragma unroll
        for (int j = 0; j < 2; j++)
          acc[m][j] = __builtin_amdgcn_mfma_f32_16x16x32_bf16(af[m], bf[j], acc[m][j], 0, 0, 0);
    }
    __syncthreads();                            // Ws reads done; A becomes fbuf
    // epilogue: +bias, bf16 -> fT global + fbuf LDS (l,d)
    #pragma unroll
    for (int m = 0; m < 4; m++) {
      int lrow = wr * 64 + m * 16 + r0;
      #pragma unroll
      for (int j = 0; j < 2; j++) {
        int dloc = wc * 32 + j * 16 + cl;
        int gcol = dch * 128 + dloc;
        float bv = conv_b[gcol];
        #pragma unroll
        for (int q = 0; q < 4; q++) {
          unsigned short h = f2bf(acc[m][j][q] + bv);
          fT[((size_t)n * HW + l0 + lrow + q) * DD + gcol] = h;
          *(unsigned short*)(fbuf + (lrow + q) * 256 + ((dloc * 2) ^ (((lrow + q) & 7) << 4))) = h;
        }
      }
    }
    __syncthreads();                            // fbuf ready
    // e-MFMA: e_acc += Cbs(64k x 128d) * fbuf(128l x 128d)^T, wave tile 32k x 32l
    #pragma unroll
    for (int kk = 0; kk < 128; kk += 32) {
      int d0 = kk + ((lane >> 4) << 3);
      bfrag ca[2], fb[2];
      #pragma unroll
      for (int m2 = 0; m2 < 2; m2++) {
        int k2 = wr * 32 + m2 * 16 + (lane & 15);
        ca[m2] = *(const bfrag*)(Cbs + k2 * 256 + ((d0 * 2) ^ ((k2 & 7) << 4)));
      }
      #pragma unroll
      for (int j2 = 0; j2 < 2; j2++) {
        int l2 = wc * 32 + j2 * 16 + (lane & 15);
        fb[j2] = *(const bfrag*)(fbuf + l2 * 256 + ((d0 * 2) ^ ((l2 & 7) << 4)));
      }
      #pragma unroll
      for (int m2 = 0; m2 < 2; m2++)
        #pragma unroll
        for (int j2 = 0; j2 < 2; j2++)
          e_acc[m2][j2] = __builtin_amdgcn_mfma_f32_16x16x32_bf16(ca[m2], fb[j2], e_acc[m2][j2], 0, 0, 0);
    }
  }

  // P5: exp + e write + rowsum partials
  __syncthreads();                              // Cbs dead -> ps
  float rs[2][4] = {{0.f,0.f,0.f,0.f},{0.f,0.f,0.f,0.f}};
  #pragma unroll
  for (int m2 = 0; m2 < 2; m2++) {
    int k2 = wr * 32 + m2 * 16 + r0;
    #pragma unroll
    for (int j2 = 0; j2 < 2; j2++) {
      int l2 = wc * 32 + j2 * 16 + cl;
      #pragma unroll
      for (int q = 0; q < 4; q++) {
        float ev = __expf(e_acc[m2][j2][q]);
        e[((size_t)n * KC + k2 + q) * HW + l0 + l2] = f2bf(ev);
        rs[m2][q] += ev;
      }
    }
  }
  #pragma unroll
  for (int m2 = 0; m2 < 2; m2++)
    #pragma unroll
    for (int q = 0; q < 4; q++) {
      float v = rs[m2][q];
      v += __shfl_xor(v, 1); v += __shfl_xor(v, 2);
      v += __shfl_xor(v, 4); v += __shfl_xor(v, 8);
      if (cl == 0) ps[(wr * 32 + m2 * 16 + r0 + q) * 4 + wc] = v;
    }
  __syncthreads();
  if (t < 64)
    psums[((size_t)n * 32 + blockIdx.x) * 64 + t] =
        ps[t * 4] + ps[t * 4 + 1] + ps[t * 4 + 2] + ps[t * 4 + 3];
}

// ---------- rinv[n,k] = 1 / sum_tn psums ----------
__global__ __launch_bounds__(256) void k_rinv(const float* __restrict__ psums,
                                              float* __restrict__ rinv) {
  int i = blockIdx.x * 256 + threadIdx.x;       // 1024 total
  int n = i >> 6, k = i & 63;
  float s = 0.f;
  #pragma unroll
  for (int tn = 0; tn < 32; tn++) s += psums[((size_t)n * 32 + tn) * 64 + k];
  rinv[i] = 1.0f / s;
}

// ---------- vlad partials: part[sk,n,k,d] = sum_l e[n,k,l] f[n,l,d] ----------
// Grid 256 blocks, XCD-grouped so the 4 dt-blocks of one (n,sk) share an XCD
// (3 of 4 e-chunk reads become L2 hits). Block 256 = 4 waves (2x2), BK=128.
__global__ __launch_bounds__(256) void k_vlad(const unsigned short* __restrict__ e,
                                              const unsigned short* __restrict__ fT,
                                              float* __restrict__ part) {
  __shared__ __align__(16) char smem[49152];
  char* As = smem;            // [64k][128l]: byte = k*256 + ((l*2)^((k&7)<<4))
  char* Bs = smem + 16384;    // [128d][128l]: byte = d*256 + ((l*2)^(((d&7)^((d>>3)&7))<<4))
  int t = threadIdx.x, lane = t & 63, wid = t >> 6;
  int wr = wid >> 1, wc = wid & 1;
  int lin = blockIdx.x;
  int xcd = lin & 7, jj = lin >> 3;
  int grp = xcd * 8 + (jj >> 2);                // 0..63 = (n,sk)
  int dt = jj & 3, n = grp >> 2, sk = grp & 3;
  int dbase = dt * 128;
  facc acc[2][4];
  facc zero = {0.f, 0.f, 0.f, 0.f};
  #pragma unroll
  for (int m = 0; m < 2; m++)
    #pragma unroll
    for (int j = 0; j < 4; j++) acc[m][j] = zero;

  for (int ks = 0; ks < 8; ks++) {
    int l0 = sk * 1024 + ks * 128;
    // stage A (e-tile 64k x 128l), swizzled b128 writes
    #pragma unroll
    for (int q = 0; q < 4; q++) {
      int ch = q * 256 + t;                      // k = ch>>4, lc = ch&15
      int k = ch >> 4, lc = ch & 15;
      bfrag v = *(const bfrag*)(e + ((size_t)n * KC + k) * HW + l0 + lc * 8);
      *(bfrag*)(As + k * 256 + ((lc * 16) ^ ((k & 7) << 4))) = v;
    }
    // stage B transposed (fT rows l -> Bs[d][l]), swizzled scalar writes
    #pragma unroll
    for (int q = 0; q < 8; q++) {
      int ch = q * 256 + t;                      // l = ch>>4, dc = ch&15
      int l = ch >> 4, dc = ch & 15;
      bfrag v = *(const bfrag*)(fT + ((size_t)n * HW + l0 + l) * DD + dbase + dc * 8);
      #pragma unroll
      for (int i = 0; i < 8; i++) {
        int d = dc * 8 + i;
        int swz = (((d & 7) ^ ((d >> 3) & 7)) << 4);
        *(unsigned short*)(Bs + d * 256 + ((l * 2) ^ swz)) = (unsigned short)v[i];
      }
    }
    __syncthreads();
    #pragma unroll
    for (int kk = 0; kk < 128; kk += 32) {
      int lk = kk + ((lane >> 4) << 3);
      bfrag af[2], bf[4];
      #pragma unroll
      for (int m = 0; m < 2; m++) {
        int krow = wr * 32 + m * 16 + (lane & 15);
        af[m] = *(const bfrag*)(As + krow * 256 + ((lk * 2) ^ ((krow & 7) << 4)));
      }
      #pragma unroll
      for (int j = 0; j < 4; j++) {
        int d = wc * 64 + j * 16 + (lane & 15);
        int swz = (((d & 7) ^ ((d >> 3) & 7)) << 4);
        bf[j] = *(const bfrag*)(Bs + d * 256 + ((lk * 2) ^ swz));
      }
      #pragma unroll
      for (int m = 0; m < 2; m++)
        #pragma unroll
        for (int j = 0; j < 4; j++)
          acc[m][j] = __builtin_amdgcn_mfma_f32_16x16x32_bf16(af[m], bf[j], acc[m][j], 0, 0, 0);
    }
    __syncthreads();
  }
  int r0 = (lane >> 4) << 2, cl = lane & 15;
  size_t base = ((size_t)(sk * NB + n)) * (KC * DD);
  #pragma unroll
  for (int m = 0; m < 2; m++) {
    int krow = wr * 32 + m * 16 + r0;
    #pragma unroll
    for (int j = 0; j < 4; j++) {
      int d = dbase + wc * 64 + j * 16 + cl;
      #pragma unroll
      for (int q = 0; q < 4; q++)
        part[base + (size_t)(krow + q) * DD + d] = acc[m][j][q];
    }
  }
}

// ---------- reduce split-K partials (4) and normalize by rinv ----------
__global__ __launch_bounds__(256) void k_reduce(const float* __restrict__ part,
                                                const float* __restrict__ rinv,
                                                float* __restrict__ out) {
  int i = blockIdx.x * 256 + threadIdx.x;
  float s = 0.f;
  #pragma unroll
  for (int skk = 0; skk < 4; skk++) s += part[(size_t)skk * (NB * KC * DD) + i];
  out[i] = s * rinv[i >> 9];                    // i>>9 = n*64+k
}

extern "C" void kernel_launch(void* const* d_in, const int* in_sizes, int n_in,
                              void* d_out, int out_size, void* d_ws, size_t ws_size,
                              hipStream_t stream) {
  const float* x         = (const float*)d_in[0];
  const float* conv_w    = (const float*)d_in[1];
  const float* conv_b    = (const float*)d_in[2];
  const float* centroids = (const float*)d_in[3];
  float* out = (float*)d_out;
  char* ws = (char*)d_ws;

  // ws layout (bytes):
  //   Wb    @ 0          (128 KB)   conv_w bf16 (D,C)
  //   Cb    @ 131072     (64 KB)    normalized centroids bf16 (K,D)
  //   fT    @ 196608     (64 MB)    f bf16 (N,L,D)
  //   e     @ 67305472   (8 MB)     exp(logits) bf16 (N,K,L)
  //   psums @ 75694080   (128 KB)   per-tile row sums fp32 (N,32,K)
  //   rinv  @ 75825152   (4 KB)     1/rowsum fp32 (N,K)
  //   part  @ 75829248   (8 MB)     vlad partials fp32 (4,N,K,D)
  unsigned short* Wb   = (unsigned short*)(ws);
  unsigned short* Cb   = (unsigned short*)(ws + 131072);
  unsigned short* fT   = (unsigned short*)(ws + 196608);
  unsigned short* ebuf = (unsigned short*)(ws + 67305472ull);
  float*          psums= (float*)(ws + 75694080ull);
  float*          rinv = (float*)(ws + 75825152ull);
  float*          part = (float*)(ws + 75829248ull);

  k_prep<<<dim3(96), dim3(256), 0, stream>>>(conv_w, centroids, Wb, Cb);

  // fused xnorm + projection + logits/exp -> fT, e, psums
  k_xproj<<<dim3(32, NB), dim3(512), 0, stream>>>(x, Wb, Cb, conv_b, fT, ebuf, psums);

  k_rinv<<<dim3(4), dim3(256), 0, stream>>>(psums, rinv);

  // vlad partials: e(K,L) * f(L,D), split-L into 4 chunks of 1024
  k_vlad<<<dim3(256), dim3(256), 0, stream>>>(ebuf, fT, part);

  k_reduce<<<dim3(NB * KC * DD / 256), dim3(256), 0, stream>>>(part, rinv, out);

  (void)in_sizes; (void)n_in; (void)out_size; (void)ws_size;
}

// Round 7
// 69.834 us; speedup vs baseline: 1.3159x; 1.3159x over previous
//
#include <hip/hip_runtime.h>

#define NB 16     // batch
#define CD 128    // channels
#define HW 4096   // spatial L
#define DD 512    // projected dim
#define KC 64     // clusters

typedef __attribute__((ext_vector_type(8))) short bfrag;           // 8 bf16 (4 VGPR)
typedef __attribute__((ext_vector_type(8))) unsigned short upk8;   // 8 bf16
typedef __attribute__((ext_vector_type(4))) float facc;            // MFMA acc
typedef __attribute__((ext_vector_type(4))) unsigned short upk4;   // 4 bf16

__device__ __forceinline__ unsigned short f2bf(float f) {
  union { float f; unsigned u; } v; v.f = f;
  unsigned r = v.u + 0x7fffu + ((v.u >> 16) & 1u);   // RNE
  return (unsigned short)(r >> 16);
}
__device__ __forceinline__ float bf2f(unsigned short h) {
  union { unsigned u; float f; } v; v.u = ((unsigned)h) << 16; return v.f;
}

// ---------- prep: centroid L2-normalize -> bf16 ; conv_w -> bf16 ----------
__global__ __launch_bounds__(256) void k_prep(const float* __restrict__ conv_w,
                                              const float* __restrict__ centroids,
                                              unsigned short* __restrict__ Wb,
                                              unsigned short* __restrict__ Cb) {
  int b = blockIdx.x, t = threadIdx.x;
  if (b < KC) {
    const float* row = centroids + (size_t)b * DD;
    float v0 = row[t], v1 = row[t + 256];
    float ss = v0 * v0 + v1 * v1;
    #pragma unroll
    for (int off = 32; off; off >>= 1) ss += __shfl_xor(ss, off);
    __shared__ float red[4];
    if ((t & 63) == 0) red[t >> 6] = ss;
    __syncthreads();
    float tot = red[0] + red[1] + red[2] + red[3];
    float inv = 1.0f / fmaxf(sqrtf(tot), 1e-12f);
    Cb[(size_t)b * DD + t]       = f2bf(v0 * inv);
    Cb[(size_t)b * DD + t + 256] = f2bf(v1 * inv);
  } else {
    int i = (b - KC) * 2048 + t * 8;            // 32 blocks cover 65536 elems
    const float4* src = (const float4*)(conv_w + i);
    float4 a = src[0], c = src[1];
    upk4 w0, w1;
    w0[0] = f2bf(a.x); w0[1] = f2bf(a.y); w0[2] = f2bf(a.z); w0[3] = f2bf(a.w);
    w1[0] = f2bf(c.x); w1[1] = f2bf(c.y); w1[2] = f2bf(c.z); w1[3] = f2bf(c.w);
    *(upk4*)(Wb + i)     = w0;
    *(upk4*)(Wb + i + 4) = w1;
  }
}

// ---------- fused xnorm + projection + logits/exp ----------
// Per block (n, l-chunk of 128):
//   P1-P3: x fp32 -> x-hat bf16 (Xn, LDS)
//   P4 (4 d-chunks): f = Xn*Wb^T + b -> fbuf LDS -> coalesced fT dump;
//                    e_acc += Cb_chunk * fbuf^T
//   P5: e = exp(e_acc) -> LDS tile -> coalesced e dump; rowsums -> psums
// LDS: A [0,32K): xt / Ws / fbuf / ps ; B [32K,64K): psum / Xn ; C [64K,80K): Cbs / e-tile
__global__ __launch_bounds__(512, 4) void k_xproj(const float* __restrict__ x,
                                                  const unsigned short* __restrict__ Wb,
                                                  const unsigned short* __restrict__ Cb,
                                                  const float* __restrict__ conv_b,
                                                  unsigned short* __restrict__ fT,
                                                  unsigned short* __restrict__ e,
                                                  float* __restrict__ psums) {
  __shared__ __align__(16) char smem[81920];
  char* xt   = smem;                      // (c,l): byte = c*256 + ((l*2)^((c&7)<<4))
  char* Xn   = smem + 32768;              // (l,c): byte = l*256 + ((c*2)^((l&7)<<4))
  float* psum = (float*)(smem + 32768);   // [4][128], dead before Xn writes
  char* Ws   = smem;                      // (d,c) chunk, aliases xt (dead after P3)
  char* fbuf = smem;                      // (l,d) chunk, aliases Ws (dead after f-MFMA)
  float* ps  = (float*)(smem);            // [64][4], region A (dead after last dump)
  char* Cbs  = smem + 65536;              // (k,d) chunk: byte = k*256 + ((d*2)^((k&7)<<4))
  char* etile = smem + 65536;             // (k,l) 64x256B, aliases Cbs (dead after loop)
  int n = blockIdx.y, l0 = blockIdx.x * 128;
  int t = threadIdx.x, lane = t & 63, wid = t >> 6;

  // P1: load x rows (c, 512B each) -> bf16 -> xt swizzled
  {
    int c = t >> 2;
    const float* xrow = x + ((size_t)n * CD + c) * HW + l0;
    #pragma unroll
    for (int j = 0; j < 8; j++) {
      int fq = (t & 3) + 4 * j;                 // float4 slot; l = fq*4
      float4 v = *(const float4*)(xrow + fq * 4);
      upk4 w;
      w[0] = f2bf(v.x); w[1] = f2bf(v.y); w[2] = f2bf(v.z); w[3] = f2bf(v.w);
      *(upk4*)(xt + c * 256 + ((fq * 8) ^ ((c & 7) << 4))) = w;
    }
  }
  __syncthreads();
  // P2: per-l sum of squares (partials over 4 c-ranges)
  {
    int l = t & 127, ch = t >> 7;
    float ss = 0.f;
    #pragma unroll
    for (int i = 0; i < 32; i++) {
      int c = ch * 32 + i;
      float v = bf2f(*(const unsigned short*)(xt + c * 256 + (((l * 2)) ^ ((c & 7) << 4))));
      ss += v * v;
    }
    psum[ch * 128 + l] = ss;
  }
  __syncthreads();
  // P3: inv per l; write Xn (l,c) swizzled
  {
    int l = t >> 2, cb = (t & 3) * 32;
    float tot = psum[l] + psum[128 + l] + psum[256 + l] + psum[384 + l];
    float inv = 1.0f / fmaxf(sqrtf(tot), 1e-12f);
    __syncthreads();                            // psum reads done before Xn writes
    #pragma unroll
    for (int g = 0; g < 4; g++) {
      int cc = cb + g * 8;
      upk8 w;
      #pragma unroll
      for (int i = 0; i < 8; i++) {
        int c = cc + i;
        float v = bf2f(*(const unsigned short*)(xt + c * 256 + (((l * 2)) ^ ((c & 7) << 4))));
        w[i] = f2bf(v * inv);
      }
      *(upk8*)(Xn + l * 256 + ((cc * 2) ^ ((l & 7) << 4))) = w;
    }
  }

  // P4: 4 d-chunks of 128. 8 waves 2x4: f-tile 64l x 32d; e-tile 32k x 32l.
  int wr = wid >> 2, wc = wid & 3;
  int r0 = (lane >> 4) << 2, cl = lane & 15;
  facc e_acc[2][2];
  facc zero = {0.f, 0.f, 0.f, 0.f};
  e_acc[0][0] = zero; e_acc[0][1] = zero; e_acc[1][0] = zero; e_acc[1][1] = zero;

  for (int dch = 0; dch < 4; dch++) {
    __syncthreads();                            // xt/fbuf/Cbs reads done
    {   // stage Ws (Wb chunk, 128d x 128c) swizzled
      int d = t >> 2;
      const unsigned short* wrow = Wb + (size_t)(dch * 128 + d) * CD;
      #pragma unroll
      for (int j = 0; j < 4; j++) {
        int ch16 = (t & 3) + 4 * j;             // 16B chunk; c0 = ch16*8
        bfrag v = *(const bfrag*)(wrow + ch16 * 8);
        *(bfrag*)(Ws + d * 256 + ((ch16 * 16) ^ ((d & 7) << 4))) = v;
      }
    }
    {   // stage Cbs (Cb chunk, 64k x 128d) swizzled — full row (2 chunks/thread)
      int k = t >> 3;
      #pragma unroll
      for (int j = 0; j < 2; j++) {
        int c0 = ((t & 7) + 8 * j) * 8;         // element offset 0..120
        bfrag v = *(const bfrag*)(Cb + (size_t)k * DD + dch * 128 + c0);
        *(bfrag*)(Cbs + k * 256 + ((c0 * 2) ^ ((k & 7) << 4))) = v;
      }
    }
    __syncthreads();
    // f-MFMA: acc = Xn(128l x 128c) * Ws(128d x 128c)^T, wave tile 64l x 32d
    facc acc[4][2];
    #pragma unroll
    for (int m = 0; m < 4; m++) { acc[m][0] = zero; acc[m][1] = zero; }
    #pragma unroll
    for (int kk = 0; kk < 128; kk += 32) {
      int c0 = kk + ((lane >> 4) << 3);
      bfrag af[4], bf[2];
      #pragma unroll
      for (int m = 0; m < 4; m++) {
        int row = wr * 64 + m * 16 + (lane & 15);
        af[m] = *(const bfrag*)(Xn + row * 256 + ((c0 * 2) ^ ((row & 7) << 4)));
      }
      #pragma unroll
      for (int j = 0; j < 2; j++) {
        int drow = wc * 32 + j * 16 + (lane & 15);
        bf[j] = *(const bfrag*)(Ws + drow * 256 + ((c0 * 2) ^ ((drow & 7) << 4)));
      }
      #pragma unroll
      for (int m = 0; m < 4; m++)
        #pragma unroll
        for (int j = 0; j < 2; j++)
          acc[m][j] = __builtin_amdgcn_mfma_f32_16x16x32_bf16(af[m], bf[j], acc[m][j], 0, 0, 0);
    }
    __syncthreads();                            // Ws reads done; A becomes fbuf
    // epilogue: +bias, bf16 -> fbuf LDS only (swizzled)
    #pragma unroll
    for (int m = 0; m < 4; m++) {
      int lrow = wr * 64 + m * 16 + r0;
      #pragma unroll
      for (int j = 0; j < 2; j++) {
        int dloc = wc * 32 + j * 16 + cl;
        float bv = conv_b[dch * 128 + dloc];
        #pragma unroll
        for (int q = 0; q < 4; q++) {
          unsigned short h = f2bf(acc[m][j][q] + bv);
          *(unsigned short*)(fbuf + (lrow + q) * 256 + ((dloc * 2) ^ (((lrow + q) & 7) << 4))) = h;
        }
      }
    }
    __syncthreads();                            // fbuf ready
    // coalesced dump fbuf -> fT (issued first: store drain overlaps e-MFMA)
    #pragma unroll
    for (int p = 0; p < 4; p++) {
      int ch = p * 512 + t;                     // 2048 x 16B chunks
      int l = ch >> 4, cj = ch & 15;
      bfrag v = *(const bfrag*)(fbuf + l * 256 + ((cj * 16) ^ ((l & 7) << 4)));
      *(bfrag*)(fT + ((size_t)n * HW + l0 + l) * DD + dch * 128 + cj * 8) = v;
    }
    // e-MFMA: e_acc += Cbs(64k x 128d) * fbuf(128l x 128d)^T, wave tile 32k x 32l
    #pragma unroll
    for (int kk = 0; kk < 128; kk += 32) {
      int d0 = kk + ((lane >> 4) << 3);
      bfrag ca[2], fb[2];
      #pragma unroll
      for (int m2 = 0; m2 < 2; m2++) {
        int k2 = wr * 32 + m2 * 16 + (lane & 15);
        ca[m2] = *(const bfrag*)(Cbs + k2 * 256 + ((d0 * 2) ^ ((k2 & 7) << 4)));
      }
      #pragma unroll
      for (int j2 = 0; j2 < 2; j2++) {
        int l2 = wc * 32 + j2 * 16 + (lane & 15);
        fb[j2] = *(const bfrag*)(fbuf + l2 * 256 + ((d0 * 2) ^ ((l2 & 7) << 4)));
      }
      #pragma unroll
      for (int m2 = 0; m2 < 2; m2++)
        #pragma unroll
        for (int j2 = 0; j2 < 2; j2++)
          e_acc[m2][j2] = __builtin_amdgcn_mfma_f32_16x16x32_bf16(ca[m2], fb[j2], e_acc[m2][j2], 0, 0, 0);
    }
  }

  // P5: exp -> e-tile LDS (region C) + rowsum partials (region A); coalesced dump
  __syncthreads();                              // Cbs / fbuf reads done
  float rs[2][4] = {{0.f,0.f,0.f,0.f},{0.f,0.f,0.f,0.f}};
  #pragma unroll
  for (int m2 = 0; m2 < 2; m2++) {
    #pragma unroll
    for (int j2 = 0; j2 < 2; j2++) {
      int l2 = wc * 32 + j2 * 16 + cl;
      #pragma unroll
      for (int q = 0; q < 4; q++) {
        int k2 = wr * 32 + m2 * 16 + r0 + q;
        float ev = __expf(e_acc[m2][j2][q]);
        *(unsigned short*)(etile + k2 * 256 + ((l2 * 2) ^ ((k2 & 7) << 4))) = f2bf(ev);
        rs[m2][q] += ev;
      }
    }
  }
  #pragma unroll
  for (int m2 = 0; m2 < 2; m2++)
    #pragma unroll
    for (int q = 0; q < 4; q++) {
      float v = rs[m2][q];
      v += __shfl_xor(v, 1); v += __shfl_xor(v, 2);
      v += __shfl_xor(v, 4); v += __shfl_xor(v, 8);
      if (cl == 0) ps[(wr * 32 + m2 * 16 + r0 + q) * 4 + wc] = v;
    }
  __syncthreads();
  // coalesced dump e-tile -> e (256B rows)
  #pragma unroll
  for (int p = 0; p < 2; p++) {
    int ch = p * 512 + t;                       // 1024 x 16B chunks
    int k = ch >> 4, cj = ch & 15;
    bfrag v = *(const bfrag*)(etile + k * 256 + ((cj * 16) ^ ((k & 7) << 4)));
    *(bfrag*)(e + ((size_t)n * KC + k) * HW + l0 + cj * 8) = v;
  }
  if (t < 64)
    psums[((size_t)n * 32 + blockIdx.x) * 64 + t] =
        ps[t * 4] + ps[t * 4 + 1] + ps[t * 4 + 2] + ps[t * 4 + 3];
}

// ---------- rinv[n,k] = 1 / sum_tn psums ----------
__global__ __launch_bounds__(256) void k_rinv(const float* __restrict__ psums,
                                              float* __restrict__ rinv) {
  int i = blockIdx.x * 256 + threadIdx.x;       // 1024 total
  int n = i >> 6, k = i & 63;
  float s = 0.f;
  #pragma unroll
  for (int tn = 0; tn < 32; tn++) s += psums[((size_t)n * 32 + tn) * 64 + k];
  rinv[i] = 1.0f / s;
}

// ---------- vlad partials: part[sk,n,k,d] = sum_l e[n,k,l] f[n,l,d] ----------
// Grid 256 blocks, XCD-grouped so the 4 dt-blocks of one (n,sk) share an XCD.
__global__ __launch_bounds__(256) void k_vlad(const unsigned short* __restrict__ e,
                                              const unsigned short* __restrict__ fT,
                                              float* __restrict__ part) {
  __shared__ __align__(16) char smem[49152];
  char* As = smem;            // [64k][128l]: byte = k*256 + ((l*2)^((k&7)<<4))
  char* Bs = smem + 16384;    // [128d][128l]: byte = d*256 + ((l*2)^(((d&7)^((d>>3)&7))<<4))
  int t = threadIdx.x, lane = t & 63, wid = t >> 6;
  int wr = wid >> 1, wc = wid & 1;
  int lin = blockIdx.x;
  int xcd = lin & 7, jj = lin >> 3;
  int grp = xcd * 8 + (jj >> 2);                // 0..63 = (n,sk)
  int dt = jj & 3, n = grp >> 2, sk = grp & 3;
  int dbase = dt * 128;
  facc acc[2][4];
  facc zero = {0.f, 0.f, 0.f, 0.f};
  #pragma unroll
  for (int m = 0; m < 2; m++)
    #pragma unroll
    for (int j = 0; j < 4; j++) acc[m][j] = zero;

  for (int ks = 0; ks < 8; ks++) {
    int l0 = sk * 1024 + ks * 128;
    // stage A (e-tile 64k x 128l), swizzled b128 writes
    #pragma unroll
    for (int q = 0; q < 4; q++) {
      int ch = q * 256 + t;                      // k = ch>>4, lc = ch&15
      int k = ch >> 4, lc = ch & 15;
      bfrag v = *(const bfrag*)(e + ((size_t)n * KC + k) * HW + l0 + lc * 8);
      *(bfrag*)(As + k * 256 + ((lc * 16) ^ ((k & 7) << 4))) = v;
    }
    // stage B transposed (fT rows l -> Bs[d][l]), swizzled scalar writes
    #pragma unroll
    for (int q = 0; q < 8; q++) {
      int ch = q * 256 + t;                      // l = ch>>4, dc = ch&15
      int l = ch >> 4, dc = ch & 15;
      bfrag v = *(const bfrag*)(fT + ((size_t)n * HW + l0 + l) * DD + dbase + dc * 8);
      #pragma unroll
      for (int i = 0; i < 8; i++) {
        int d = dc * 8 + i;
        int swz = (((d & 7) ^ ((d >> 3) & 7)) << 4);
        *(unsigned short*)(Bs + d * 256 + ((l * 2) ^ swz)) = (unsigned short)v[i];
      }
    }
    __syncthreads();
    #pragma unroll
    for (int kk = 0; kk < 128; kk += 32) {
      int lk = kk + ((lane >> 4) << 3);
      bfrag af[2], bf[4];
      #pragma unroll
      for (int m = 0; m < 2; m++) {
        int krow = wr * 32 + m * 16 + (lane & 15);
        af[m] = *(const bfrag*)(As + krow * 256 + ((lk * 2) ^ ((krow & 7) << 4)));
      }
      #pragma unroll
      for (int j = 0; j < 4; j++) {
        int d = wc * 64 + j * 16 + (lane & 15);
        int swz = (((d & 7) ^ ((d >> 3) & 7)) << 4);
        bf[j] = *(const bfrag*)(Bs + d * 256 + ((lk * 2) ^ swz));
      }
      #pragma unroll
      for (int m = 0; m < 2; m++)
        #pragma unroll
        for (int j = 0; j < 4; j++)
          acc[m][j] = __builtin_amdgcn_mfma_f32_16x16x32_bf16(af[m], bf[j], acc[m][j], 0, 0, 0);
    }
    __syncthreads();
  }
  int r0 = (lane >> 4) << 2, cl = lane & 15;
  size_t base = ((size_t)(sk * NB + n)) * (KC * DD);
  #pragma unroll
  for (int m = 0; m < 2; m++) {
    int krow = wr * 32 + m * 16 + r0;
    #pragma unroll
    for (int j = 0; j < 4; j++) {
      int d = dbase + wc * 64 + j * 16 + cl;
      #pragma unroll
      for (int q = 0; q < 4; q++)
        part[base + (size_t)(krow + q) * DD + d] = acc[m][j][q];
    }
  }
}

// ---------- reduce split-K partials (4) and normalize by rinv ----------
__global__ __launch_bounds__(256) void k_reduce(const float* __restrict__ part,
                                                const float* __restrict__ rinv,
                                                float* __restrict__ out) {
  int i = blockIdx.x * 256 + threadIdx.x;
  float s = 0.f;
  #pragma unroll
  for (int skk = 0; skk < 4; skk++) s += part[(size_t)skk * (NB * KC * DD) + i];
  out[i] = s * rinv[i >> 9];                    // i>>9 = n*64+k
}

extern "C" void kernel_launch(void* const* d_in, const int* in_sizes, int n_in,
                              void* d_out, int out_size, void* d_ws, size_t ws_size,
                              hipStream_t stream) {
  const float* x         = (const float*)d_in[0];
  const float* conv_w    = (const float*)d_in[1];
  const float* conv_b    = (const float*)d_in[2];
  const float* centroids = (const float*)d_in[3];
  float* out = (float*)d_out;
  char* ws = (char*)d_ws;

  // ws layout (bytes):
  //   Wb    @ 0          (128 KB)   conv_w bf16 (D,C)
  //   Cb    @ 131072     (64 KB)    normalized centroids bf16 (K,D)
  //   fT    @ 196608     (64 MB)    f bf16 (N,L,D)
  //   e     @ 67305472   (8 MB)     exp(logits) bf16 (N,K,L)
  //   psums @ 75694080   (128 KB)   per-tile row sums fp32 (N,32,K)
  //   rinv  @ 75825152   (4 KB)     1/rowsum fp32 (N,K)
  //   part  @ 75829248   (8 MB)     vlad partials fp32 (4,N,K,D)
  unsigned short* Wb   = (unsigned short*)(ws);
  unsigned short* Cb   = (unsigned short*)(ws + 131072);
  unsigned short* fT   = (unsigned short*)(ws + 196608);
  unsigned short* ebuf = (unsigned short*)(ws + 67305472ull);
  float*          psums= (float*)(ws + 75694080ull);
  float*          rinv = (float*)(ws + 75825152ull);
  float*          part = (float*)(ws + 75829248ull);

  k_prep<<<dim3(96), dim3(256), 0, stream>>>(conv_w, centroids, Wb, Cb);

  // fused xnorm + projection + logits/exp -> fT, e, psums
  k_xproj<<<dim3(32, NB), dim3(512), 0, stream>>>(x, Wb, Cb, conv_b, fT, ebuf, psums);

  k_rinv<<<dim3(4), dim3(256), 0, stream>>>(psums, rinv);

  // vlad partials: e(K,L) * f(L,D), split-L into 4 chunks of 1024
  k_vlad<<<dim3(256), dim3(256), 0, stream>>>(ebuf, fT, part);

  k_reduce<<<dim3(NB * KC * DD / 256), dim3(256), 0, stream>>>(part, rinv, out);

  (void)in_sizes; (void)n_in; (void)out_size; (void)ws_size;
}